// Round 2
// 19313.881 us; speedup vs baseline: 1.2368x; 1.2368x over previous
//
#include <hip/hip_runtime.h>
#include <math.h>

// Problem constants (match reference)
constexpr int B_  = 2;
constexpr int S_  = 1024;
constexpr int E_  = 1024;   // = NH*AH
constexpr int NH_ = 16;
constexpr int AH_ = 64;
constexpr int NL_ = 4;
constexpr int HC_ = 2048;
constexpr int V_  = 32000;
constexpr int T_  = B_ * S_;          // 2048 token rows
constexpr int EE_ = E_ * E_;          // per-layer weight stride

typedef short bf16x8 __attribute__((ext_vector_type(8)));   // 8 bf16 = 4 VGPR (MFMA A/B frag)
typedef float f32x4  __attribute__((ext_vector_type(4)));   // MFMA C/D frag
typedef unsigned short us4 __attribute__((ext_vector_type(4)));

// fp32 -> (hi, lo) bf16 pair, both round-to-nearest-even.
// hi = RN-bf16(x)  -> |x-hi| <= 2^-9 |x|
// lo = RN-bf16(x-hi) -> residual quantization <= 2^-17 |x|
// a*b ~= ah*bh + al*bh + ah*bl ; dropped al*bl <= ~2^-18 relative.
__device__ __forceinline__ void split_bf16(float x, unsigned short& h, unsigned short& l) {
  unsigned u = __float_as_uint(x);
  unsigned r = u + (0x7fffu + ((u >> 16) & 1u));   // RN-even to bf16
  h = (unsigned short)(r >> 16);
  float d = x - __uint_as_float(r & 0xffff0000u);
  unsigned t = __float_as_uint(d);
  t += 0x7fffu + ((t >> 16) & 1u);
  l = (unsigned short)(t >> 16);
}

// ---------------------------------------------------------------------------
// x + positional encoding (unchanged).
// ---------------------------------------------------------------------------
__global__ __launch_bounds__(256) void add_pe_kernel(const float* __restrict__ in,
                                                     float* __restrict__ out,
                                                     int total) {
  int idx = blockIdx.x * 256 + threadIdx.x;
  if (idx >= total) return;
  int e = idx & (E_ - 1);
  int s = (idx >> 10) & (S_ - 1);        // E_=1024
  double arg = (double)s * exp(-(double)(e >> 1) * (9.210340371976184 / (double)E_));
  float pe = (e & 1) ? (float)cos(arg) : (float)sin(arg);
  out[idx] = in[idx] + pe;
}

// ---------------------------------------------------------------------------
// bf16x3 emulated-fp32 GEMM on MFMA: C[M,N] = A[M,K] @ B[K,N] (+bias)(+relu)
// 128x128 block tile, BK=32, 256 threads = 4 waves (2x2), each wave 64x64 out
// (4x4 fragments of 16x16), v_mfma_f32_16x16x32_bf16, 3 MFMAs per frag pair.
// A staged as [m][k] hi/lo bf16 in LDS; B transposed during staging to [n][k]
// so both operands are read as 8 contiguous bf16 per lane (ds_read_b128).
// LDS rows padded 32->40 halfs: fragment reads are <=2-way bank conflicts.
// Grid: x = M-blocks so consecutively dispatched blocks share the same B
// panel (L2/L3 reuse for the 256MB classifier weight).
// All M,N,K used here are multiples of 128/128/32 -> no bounds checks.
// ---------------------------------------------------------------------------
constexpr int LDH = 40;   // halfs per LDS row: 32 data + 8 pad

__global__ __launch_bounds__(256) void gemm_bf16x3(const float* __restrict__ A,
                                                   const float* __restrict__ Bm,
                                                   const float* __restrict__ bias,
                                                   float* __restrict__ C,
                                                   int M, int N, int K, int relu) {
  __shared__ unsigned short As_hi[128 * LDH];
  __shared__ unsigned short As_lo[128 * LDH];
  __shared__ unsigned short Bs_hi[128 * LDH];
  __shared__ unsigned short Bs_lo[128 * LDH];

  const int tid  = threadIdx.x;
  const int lane = tid & 63;
  const int wv   = tid >> 6;
  const int wr   = (wv >> 1) << 6;     // wave row offset in tile (0/64)
  const int wc   = (wv & 1) << 6;      // wave col offset in tile (0/64)

  const int m0 = blockIdx.x * 128;
  const int n0 = blockIdx.y * 128;

  // A staging: thread -> (row 0..127, 16-wide k half)
  const int arow = tid >> 1;
  const int ak   = (tid & 1) << 4;
  // B staging: thread -> (col 0..127, 16 k's loaded column-wise for transpose)
  const int bcol = tid >> 1;
  const int bk   = (tid & 1) << 4;

  // MFMA fragment addressing: lane l -> row l&15, k-half (l>>4)*8
  const int r16 = lane & 15;
  const int kb  = (lane >> 4) << 3;

  f32x4 acc[4][4];
#pragma unroll
  for (int i = 0; i < 4; ++i)
#pragma unroll
    for (int j = 0; j < 4; ++j) {
      f32x4 z = {0.f, 0.f, 0.f, 0.f};
      acc[i][j] = z;
    }

  const float* Arow = A + (size_t)(m0 + arow) * K + ak;
  const float* Bcol = Bm + n0 + bcol;

  for (int k0 = 0; k0 < K; k0 += 32) {
    // ---- stage A tile 128x32 (fp32 -> hi/lo bf16) ----
#pragma unroll
    for (int i = 0; i < 4; ++i) {
      float4 v = *(const float4*)&Arow[k0 + 4 * i];
      unsigned short h0, h1, h2, h3, l0, l1, l2, l3;
      split_bf16(v.x, h0, l0);
      split_bf16(v.y, h1, l1);
      split_bf16(v.z, h2, l2);
      split_bf16(v.w, h3, l3);
      us4 hv = {h0, h1, h2, h3};
      us4 lv = {l0, l1, l2, l3};
      *(us4*)&As_hi[arow * LDH + ak + 4 * i] = hv;
      *(us4*)&As_lo[arow * LDH + ak + 4 * i] = lv;
    }
    // ---- stage B tile 32x128, transposed to [n][k] ----
    float bvv[16];
#pragma unroll
    for (int i = 0; i < 16; ++i) {
      bvv[i] = Bcol[(size_t)(k0 + bk + i) * N];
    }
#pragma unroll
    for (int i = 0; i < 4; ++i) {
      unsigned short h0, h1, h2, h3, l0, l1, l2, l3;
      split_bf16(bvv[4 * i + 0], h0, l0);
      split_bf16(bvv[4 * i + 1], h1, l1);
      split_bf16(bvv[4 * i + 2], h2, l2);
      split_bf16(bvv[4 * i + 3], h3, l3);
      us4 hv = {h0, h1, h2, h3};
      us4 lv = {l0, l1, l2, l3};
      *(us4*)&Bs_hi[bcol * LDH + bk + 4 * i] = hv;
      *(us4*)&Bs_lo[bcol * LDH + bk + 4 * i] = lv;
    }
    __syncthreads();

    // ---- fragment loads (ds_read_b128 each) ----
    bf16x8 ah[4], al[4], bh[4], bl[4];
#pragma unroll
    for (int m = 0; m < 4; ++m) {
      const int row = wr + m * 16 + r16;
      ah[m] = *(const bf16x8*)&As_hi[row * LDH + kb];
      al[m] = *(const bf16x8*)&As_lo[row * LDH + kb];
    }
#pragma unroll
    for (int n = 0; n < 4; ++n) {
      const int col = wc + n * 16 + r16;
      bh[n] = *(const bf16x8*)&Bs_hi[col * LDH + kb];
      bl[n] = *(const bf16x8*)&Bs_lo[col * LDH + kb];
    }

    // ---- 3-term MFMA: hi*hi + lo*hi + hi*lo, fp32 accumulate ----
#pragma unroll
    for (int m = 0; m < 4; ++m)
#pragma unroll
      for (int n = 0; n < 4; ++n) {
        acc[m][n] = __builtin_amdgcn_mfma_f32_16x16x32_bf16(ah[m], bh[n], acc[m][n], 0, 0, 0);
        acc[m][n] = __builtin_amdgcn_mfma_f32_16x16x32_bf16(al[m], bh[n], acc[m][n], 0, 0, 0);
        acc[m][n] = __builtin_amdgcn_mfma_f32_16x16x32_bf16(ah[m], bl[n], acc[m][n], 0, 0, 0);
      }
    __syncthreads();
  }

  // ---- epilogue: C/D layout col = lane&15, row = (lane>>4)*4 + reg ----
#pragma unroll
  for (int n = 0; n < 4; ++n) {
    const int col = n0 + wc + n * 16 + r16;
    const float bv = bias ? bias[col] : 0.f;
#pragma unroll
    for (int m = 0; m < 4; ++m) {
      const int row0 = m0 + wr + m * 16 + ((lane >> 4) << 2);
#pragma unroll
      for (int r = 0; r < 4; ++r) {
        float o = acc[m][n][r] + bv;
        if (relu) o = fmaxf(o, 0.f);
        C[(size_t)(row0 + r) * N + col] = o;
      }
    }
  }
}

// ---------------------------------------------------------------------------
// Fused attention (unchanged this round): one wave per (b, h, query row).
// ---------------------------------------------------------------------------
__global__ __launch_bounds__(256) void attn_kernel(const float* __restrict__ Q,
                                                   const float* __restrict__ Kp,
                                                   const float* __restrict__ Vp,
                                                   float* __restrict__ O,
                                                   int causal) {
  __shared__ float qs[4][64];
  __shared__ float ps[4][S_];

  const int lane = threadIdx.x & 63;
  const int wv   = threadIdx.x >> 6;
  const int w    = blockIdx.x * 4 + wv;
  const int row  = w & (S_ - 1);
  const int h    = (w >> 10) & (NH_ - 1);
  const int b    = w >> 14;   // / (S_*NH_)
  const float scale = 0.125f; // 1/sqrt(64)

  const size_t qoff  = ((size_t)(b * S_ + row)) * E_ + h * AH_;
  const size_t kbase = ((size_t)b * S_) * E_ + h * AH_;

  qs[wv][lane] = Q[qoff + lane];
  __syncthreads();

  // ---- phase 1: scores ----
  float s[16];
  float mx = -3.0e38f;
#pragma unroll 4
  for (int t = 0; t < 16; ++t) {
    const int j = t * 64 + lane;
    const float* kr = Kp + kbase + (size_t)j * E_;
    float dot = 0.f;
#pragma unroll
    for (int d4 = 0; d4 < 64; d4 += 4) {
      float4 kv = *(const float4*)&kr[d4];
      dot += qs[wv][d4 + 0] * kv.x;
      dot += qs[wv][d4 + 1] * kv.y;
      dot += qs[wv][d4 + 2] * kv.z;
      dot += qs[wv][d4 + 3] * kv.w;
    }
    float sc = dot * scale;
    if (causal && j > row) sc = -1.0e9f;   // matches reference mask add
    s[t] = sc;
    mx = fmaxf(mx, sc);
  }
#pragma unroll
  for (int off = 32; off; off >>= 1) mx = fmaxf(mx, __shfl_xor(mx, off, 64));

  float sum = 0.f;
#pragma unroll
  for (int t = 0; t < 16; ++t) {
    float p = expf(s[t] - mx);   // masked entries underflow to exactly 0
    sum += p;
    ps[wv][t * 64 + lane] = p;
  }
#pragma unroll
  for (int off = 32; off; off >>= 1) sum += __shfl_xor(sum, off, 64);
  const float inv = 1.0f / sum;
  __syncthreads();

  // ---- phase 2: PV, lane owns output dim d = lane ----
  const float* vr = Vp + kbase + lane;
  const int jend = causal ? row : (S_ - 1);
  float acc = 0.f;
  int j = 0;
  for (; j + 3 <= jend; j += 4) {
    acc += ps[wv][j + 0] * vr[(size_t)(j + 0) * E_];
    acc += ps[wv][j + 1] * vr[(size_t)(j + 1) * E_];
    acc += ps[wv][j + 2] * vr[(size_t)(j + 2) * E_];
    acc += ps[wv][j + 3] * vr[(size_t)(j + 3) * E_];
  }
  for (; j <= jend; ++j) acc += ps[wv][j] * vr[(size_t)j * E_];

  O[qoff + lane] = acc * inv;
}

// ---------------------------------------------------------------------------
// out[row] = LayerNorm(X[row] + R[row]) * g + b   (unchanged)
// ---------------------------------------------------------------------------
__global__ __launch_bounds__(256) void add_ln_kernel(const float* __restrict__ X,
                                                     const float* __restrict__ R,
                                                     const float* __restrict__ g,
                                                     const float* __restrict__ bta,
                                                     float* __restrict__ out) {
  __shared__ float s1[4], s2[4];
  const int row = blockIdx.x;
  const int tid = threadIdx.x;
  const size_t base = (size_t)row * E_;
  const int e = tid * 4;

  float4 xv = *(const float4*)&X[base + e];
  float4 rv = *(const float4*)&R[base + e];
  float v0 = xv.x + rv.x, v1 = xv.y + rv.y, v2 = xv.z + rv.z, v3 = xv.w + rv.w;

  float sum = v0 + v1 + v2 + v3;
  float sq  = v0 * v0 + v1 * v1 + v2 * v2 + v3 * v3;
#pragma unroll
  for (int off = 32; off; off >>= 1) {
    sum += __shfl_xor(sum, off, 64);
    sq  += __shfl_xor(sq,  off, 64);
  }
  if ((tid & 63) == 0) { s1[tid >> 6] = sum; s2[tid >> 6] = sq; }
  __syncthreads();
  sum = s1[0] + s1[1] + s1[2] + s1[3];
  sq  = s2[0] + s2[1] + s2[2] + s2[3];

  const float mean = sum * (1.0f / E_);
  const float var  = sq * (1.0f / E_) - mean * mean;
  const float rs   = rsqrtf(var + 1e-5f);

  float4 gv = *(const float4*)&g[e];
  float4 bv = *(const float4*)&bta[e];
  float4 o;
  o.x = (v0 - mean) * rs * gv.x + bv.x;
  o.y = (v1 - mean) * rs * gv.y + bv.y;
  o.z = (v2 - mean) * rs * gv.z + bv.z;
  o.w = (v3 - mean) * rs * gv.w + bv.w;
  *(float4*)&out[base + e] = o;
}

// ---------------------------------------------------------------------------
extern "C" void kernel_launch(void* const* d_in, const int* in_sizes, int n_in,
                              void* d_out, int out_size, void* d_ws, size_t ws_size,
                              hipStream_t stream) {
  const float* x       = (const float*)d_in[0];
  const float* y       = (const float*)d_in[1];
  const float* enc_wq  = (const float*)d_in[2];
  const float* enc_wk  = (const float*)d_in[3];
  const float* enc_wv  = (const float*)d_in[4];
  const float* enc_wo  = (const float*)d_in[5];
  const float* enc_bo  = (const float*)d_in[6];
  const float* enc_ln1g = (const float*)d_in[7];
  const float* enc_ln1b = (const float*)d_in[8];
  const float* enc_ln2g = (const float*)d_in[9];
  const float* enc_ln2b = (const float*)d_in[10];
  const float* enc_f1w = (const float*)d_in[11];
  const float* enc_f1b = (const float*)d_in[12];
  const float* enc_f2w = (const float*)d_in[13];
  const float* enc_f2b = (const float*)d_in[14];
  const float* dec_wq1 = (const float*)d_in[15];
  const float* dec_wk1 = (const float*)d_in[16];
  const float* dec_wv1 = (const float*)d_in[17];
  const float* dec_wo1 = (const float*)d_in[18];
  const float* dec_bo1 = (const float*)d_in[19];
  const float* dec_wq2 = (const float*)d_in[20];
  const float* dec_wk2 = (const float*)d_in[21];
  const float* dec_wv2 = (const float*)d_in[22];
  const float* dec_wo2 = (const float*)d_in[23];
  const float* dec_bo2 = (const float*)d_in[24];
  const float* dec_ln1g = (const float*)d_in[25];
  const float* dec_ln1b = (const float*)d_in[26];
  const float* dec_ln2g = (const float*)d_in[27];
  const float* dec_ln2b = (const float*)d_in[28];
  const float* dec_ln3g = (const float*)d_in[29];
  const float* dec_ln3b = (const float*)d_in[30];
  const float* dec_f1w = (const float*)d_in[31];
  const float* dec_f1b = (const float*)d_in[32];
  const float* dec_f2w = (const float*)d_in[33];
  const float* dec_f2b = (const float*)d_in[34];
  const float* cls_w1  = (const float*)d_in[35];
  const float* cls_b1  = (const float*)d_in[36];
  const float* cls_w2  = (const float*)d_in[37];
  const float* cls_b2  = (const float*)d_in[38];
  const float* cls_w3  = (const float*)d_in[39];
  const float* cls_b3  = (const float*)d_in[40];

  float* ws = (float*)d_ws;
  const size_t TE = (size_t)T_ * E_;   // 2M floats
  float* EX = ws + 0 * TE;             // encoder activations / encs
  float* DX = ws + 1 * TE;             // decoder activations
  float* Qb = ws + 2 * TE;
  float* Kb = ws + 3 * TE;
  float* Vb = ws + 4 * TE;
  float* AT = ws + 5 * TE;             // attention output (pre-Wo)
  float* T1 = ws + 6 * TE;
  float* T2 = ws + 7 * TE;
  float* H1 = ws + 2 * TE;             // classifier hidden 1 (2*TE floats)
  float* H2 = ws + 4 * TE;             // classifier hidden 2 (2*TE floats)

  auto gemm = [&](const float* A, const float* W, const float* bias, float* C,
                  int M, int N, int K, int relu) {
    dim3 grid(M / 128, N / 128);       // x = M-blocks: consecutive blocks share B panel
    gemm_bf16x3<<<grid, 256, 0, stream>>>(A, W, bias, C, M, N, K, relu);
  };
  auto attn = [&](const float* Qp, const float* Kp, const float* Vp, float* Op,
                  int causal) {
    const int waves = B_ * NH_ * S_;   // 32768
    attn_kernel<<<waves / 4, 256, 0, stream>>>(Qp, Kp, Vp, Op, causal);
  };
  auto add_ln = [&](const float* Xp, const float* Rp, const float* g,
                    const float* bb, float* Op) {
    add_ln_kernel<<<T_, 256, 0, stream>>>(Xp, Rp, g, bb, Op);
  };

  const int total = T_ * E_;
  add_pe_kernel<<<(total + 255) / 256, 256, 0, stream>>>(x, EX, total);
  add_pe_kernel<<<(total + 255) / 256, 256, 0, stream>>>(y, DX, total);

  // ---------------- encoder ----------------
  for (int i = 0; i < NL_; ++i) {
    const size_t wOff = (size_t)i * EE_;
    const size_t vOff = (size_t)i * E_;
    gemm(EX, enc_wq + wOff, nullptr, Qb, T_, E_, E_, 0);
    gemm(EX, enc_wk + wOff, nullptr, Kb, T_, E_, E_, 0);
    gemm(EX, enc_wv + wOff, nullptr, Vb, T_, E_, E_, 0);
    attn(Qb, Kb, Vb, AT, 0);
    gemm(AT, enc_wo + wOff, enc_bo + vOff, T1, T_, E_, E_, 0);
    add_ln(T1, EX, enc_ln1g + vOff, enc_ln1b + vOff, T2);      // fx
    gemm(T2, enc_f1w + wOff, enc_f1b + vOff, T1, T_, E_, E_, 1);
    gemm(T1, enc_f2w + wOff, enc_f2b + vOff, Qb, T_, E_, E_, 0);
    add_ln(Qb, EX, enc_ln2g + vOff, enc_ln2b + vOff, EX);      // residual to block input
  }
  // EX now holds encs

  // ---------------- decoder ----------------
  for (int i = 0; i < NL_; ++i) {
    const size_t wOff = (size_t)i * EE_;
    const size_t vOff = (size_t)i * E_;
    // masked self-attention
    gemm(DX, dec_wq1 + wOff, nullptr, Qb, T_, E_, E_, 0);
    gemm(DX, dec_wk1 + wOff, nullptr, Kb, T_, E_, E_, 0);
    gemm(DX, dec_wv1 + wOff, nullptr, Vb, T_, E_, E_, 0);
    attn(Qb, Kb, Vb, AT, 1);
    gemm(AT, dec_wo1 + wOff, dec_bo1 + vOff, T1, T_, E_, E_, 0);
    add_ln(T1, DX, dec_ln1g + vOff, dec_ln1b + vOff, T2);      // f1
    // cross-attention (q from f1, k/v from encs)
    gemm(T2, dec_wq2 + wOff, nullptr, Qb, T_, E_, E_, 0);
    gemm(EX, dec_wk2 + wOff, nullptr, Kb, T_, E_, E_, 0);
    gemm(EX, dec_wv2 + wOff, nullptr, Vb, T_, E_, E_, 0);
    attn(Qb, Kb, Vb, AT, 0);
    gemm(AT, dec_wo2 + wOff, dec_bo2 + vOff, T1, T_, E_, E_, 0);
    add_ln(T1, DX, dec_ln2g + vOff, dec_ln2b + vOff, T2);      // f2
    // FFN
    gemm(T2, dec_f1w + wOff, dec_f1b + vOff, T1, T_, E_, E_, 1);
    gemm(T1, dec_f2w + wOff, dec_f2b + vOff, Qb, T_, E_, E_, 0);
    add_ln(Qb, DX, dec_ln3g + vOff, dec_ln3b + vOff, DX);      // residual to block input
  }

  // ---------------- classifier ----------------
  gemm(DX, cls_w1, cls_b1, H1, T_, HC_, E_, 1);
  gemm(H1, cls_w2, cls_b2, H2, T_, HC_, HC_, 1);
  gemm(H2, cls_w3, cls_b3, (float*)d_out, T_, V_, HC_, 0);
}

// Round 3
// 6868.159 us; speedup vs baseline: 3.4780x; 2.8121x over previous
//
#include <hip/hip_runtime.h>
#include <math.h>

// Problem constants (match reference)
constexpr int B_  = 2;
constexpr int S_  = 1024;
constexpr int E_  = 1024;   // = NH*AH
constexpr int NH_ = 16;
constexpr int AH_ = 64;
constexpr int NL_ = 4;
constexpr int HC_ = 2048;
constexpr int V_  = 32000;
constexpr int T_  = B_ * S_;          // 2048 token rows
constexpr int EE_ = E_ * E_;          // per-layer weight stride

typedef short bf16x8 __attribute__((ext_vector_type(8)));   // 8 bf16 = 4 VGPR (MFMA A/B frag)
typedef float f32x4  __attribute__((ext_vector_type(4)));   // MFMA C/D frag
typedef unsigned short us4 __attribute__((ext_vector_type(4)));

// fp32 -> (hi, lo) bf16 pair, both round-to-nearest-even.
// hi = RN-bf16(x)  -> |x-hi| <= 2^-9 |x|
// lo = RN-bf16(x-hi) -> residual quantization <= 2^-17 |x|
// a*b ~= ah*bh + al*bh + ah*bl ; dropped al*bl <= ~2^-18 relative.
__device__ __forceinline__ void split_bf16(float x, unsigned short& h, unsigned short& l) {
  unsigned u = __float_as_uint(x);
  unsigned r = u + (0x7fffu + ((u >> 16) & 1u));   // RN-even to bf16
  h = (unsigned short)(r >> 16);
  float d = x - __uint_as_float(r & 0xffff0000u);
  unsigned t = __float_as_uint(d);
  t += 0x7fffu + ((t >> 16) & 1u);
  l = (unsigned short)(t >> 16);
}

// ---------------------------------------------------------------------------
// x + positional encoding (unchanged).
// ---------------------------------------------------------------------------
__global__ __launch_bounds__(256) void add_pe_kernel(const float* __restrict__ in,
                                                     float* __restrict__ out,
                                                     int total) {
  int idx = blockIdx.x * 256 + threadIdx.x;
  if (idx >= total) return;
  int e = idx & (E_ - 1);
  int s = (idx >> 10) & (S_ - 1);        // E_=1024
  double arg = (double)s * exp(-(double)(e >> 1) * (9.210340371976184 / (double)E_));
  float pe = (e & 1) ? (float)cos(arg) : (float)sin(arg);
  out[idx] = in[idx] + pe;
}

// ---------------------------------------------------------------------------
// bf16x3 emulated-fp32 GEMM on MFMA (unchanged from round 2, verified).
// ---------------------------------------------------------------------------
constexpr int LDH = 40;   // halfs per LDS row: 32 data + 8 pad

__global__ __launch_bounds__(256) void gemm_bf16x3(const float* __restrict__ A,
                                                   const float* __restrict__ Bm,
                                                   const float* __restrict__ bias,
                                                   float* __restrict__ C,
                                                   int M, int N, int K, int relu) {
  __shared__ unsigned short As_hi[128 * LDH];
  __shared__ unsigned short As_lo[128 * LDH];
  __shared__ unsigned short Bs_hi[128 * LDH];
  __shared__ unsigned short Bs_lo[128 * LDH];

  const int tid  = threadIdx.x;
  const int lane = tid & 63;
  const int wv   = tid >> 6;
  const int wr   = (wv >> 1) << 6;     // wave row offset in tile (0/64)
  const int wc   = (wv & 1) << 6;      // wave col offset in tile (0/64)

  const int m0 = blockIdx.x * 128;
  const int n0 = blockIdx.y * 128;

  const int arow = tid >> 1;
  const int ak   = (tid & 1) << 4;
  const int bcol = tid >> 1;
  const int bk   = (tid & 1) << 4;

  const int r16 = lane & 15;
  const int kb  = (lane >> 4) << 3;

  f32x4 acc[4][4];
#pragma unroll
  for (int i = 0; i < 4; ++i)
#pragma unroll
    for (int j = 0; j < 4; ++j) {
      f32x4 z = {0.f, 0.f, 0.f, 0.f};
      acc[i][j] = z;
    }

  const float* Arow = A + (size_t)(m0 + arow) * K + ak;
  const float* Bcol = Bm + n0 + bcol;

  for (int k0 = 0; k0 < K; k0 += 32) {
#pragma unroll
    for (int i = 0; i < 4; ++i) {
      float4 v = *(const float4*)&Arow[k0 + 4 * i];
      unsigned short h0, h1, h2, h3, l0, l1, l2, l3;
      split_bf16(v.x, h0, l0);
      split_bf16(v.y, h1, l1);
      split_bf16(v.z, h2, l2);
      split_bf16(v.w, h3, l3);
      us4 hv = {h0, h1, h2, h3};
      us4 lv = {l0, l1, l2, l3};
      *(us4*)&As_hi[arow * LDH + ak + 4 * i] = hv;
      *(us4*)&As_lo[arow * LDH + ak + 4 * i] = lv;
    }
    float bvv[16];
#pragma unroll
    for (int i = 0; i < 16; ++i) {
      bvv[i] = Bcol[(size_t)(k0 + bk + i) * N];
    }
#pragma unroll
    for (int i = 0; i < 4; ++i) {
      unsigned short h0, h1, h2, h3, l0, l1, l2, l3;
      split_bf16(bvv[4 * i + 0], h0, l0);
      split_bf16(bvv[4 * i + 1], h1, l1);
      split_bf16(bvv[4 * i + 2], h2, l2);
      split_bf16(bvv[4 * i + 3], h3, l3);
      us4 hv = {h0, h1, h2, h3};
      us4 lv = {l0, l1, l2, l3};
      *(us4*)&Bs_hi[bcol * LDH + bk + 4 * i] = hv;
      *(us4*)&Bs_lo[bcol * LDH + bk + 4 * i] = lv;
    }
    __syncthreads();

    bf16x8 ah[4], al[4], bh[4], bl[4];
#pragma unroll
    for (int m = 0; m < 4; ++m) {
      const int row = wr + m * 16 + r16;
      ah[m] = *(const bf16x8*)&As_hi[row * LDH + kb];
      al[m] = *(const bf16x8*)&As_lo[row * LDH + kb];
    }
#pragma unroll
    for (int n = 0; n < 4; ++n) {
      const int col = wc + n * 16 + r16;
      bh[n] = *(const bf16x8*)&Bs_hi[col * LDH + kb];
      bl[n] = *(const bf16x8*)&Bs_lo[col * LDH + kb];
    }

#pragma unroll
    for (int m = 0; m < 4; ++m)
#pragma unroll
      for (int n = 0; n < 4; ++n) {
        acc[m][n] = __builtin_amdgcn_mfma_f32_16x16x32_bf16(ah[m], bh[n], acc[m][n], 0, 0, 0);
        acc[m][n] = __builtin_amdgcn_mfma_f32_16x16x32_bf16(al[m], bh[n], acc[m][n], 0, 0, 0);
        acc[m][n] = __builtin_amdgcn_mfma_f32_16x16x32_bf16(ah[m], bl[n], acc[m][n], 0, 0, 0);
      }
    __syncthreads();
  }

#pragma unroll
  for (int n = 0; n < 4; ++n) {
    const int col = n0 + wc + n * 16 + r16;
    const float bv = bias ? bias[col] : 0.f;
#pragma unroll
    for (int m = 0; m < 4; ++m) {
      const int row0 = m0 + wr + m * 16 + ((lane >> 4) << 2);
#pragma unroll
      for (int r = 0; r < 4; ++r) {
        float o = acc[m][n][r] + bv;
        if (relu) o = fmaxf(o, 0.f);
        C[(size_t)(row0 + r) * N + col] = o;
      }
    }
  }
}

// ---------------------------------------------------------------------------
// MFMA flash attention, bf16x3 emulated-fp32.
// Block = 4 waves = one (b,h) x 64 q-rows (16 per wave).  KV-tiles of 64 keys
// staged in LDS as hi/lo bf16: K as [key][d], V transposed as [d][key].
// Per tile per wave: S(16x64) = 24 MFMAs; online softmax (row state in the
// C-fragment mapping, reduce via shfl_xor width 16); P -> hi/lo bf16 via
// per-wave LDS (A-frag relayout); PV = 24 MFMAs into rescaled O accumulators.
// Fragment mapping identical to gemm_bf16x3 (harness-verified):
//   A: row=lane&15, k=(lane>>4)*8 ; B: col=lane&15, k=(lane>>4)*8
//   C: col=lane&15, row=(lane>>4)*4+reg
// ---------------------------------------------------------------------------
constexpr int KP_ = 72;   // halfs per LDS row: 64 data + 8 pad (16B-aligned rows)

__global__ __launch_bounds__(256) void attn_mfma(const float* __restrict__ Qp,
                                                 const float* __restrict__ Kp,
                                                 const float* __restrict__ Vp,
                                                 float* __restrict__ Op,
                                                 int causal) {
  __shared__ unsigned short Khi[64 * KP_], Klo[64 * KP_];   // [key][d]
  __shared__ unsigned short Vhi[64 * KP_], Vlo[64 * KP_];   // [d][key] (transposed)
  __shared__ unsigned short Phi[4][16 * KP_], Plo[4][16 * KP_]; // per-wave [q][key]

  const int tid  = threadIdx.x;
  const int lane = tid & 63;
  const int wv   = tid >> 6;
  const int r16  = lane & 15;
  const int hi4  = lane >> 4;

  const int qt = blockIdx.x;            // q-tile index (64 rows each)
  const int bh = blockIdx.y;
  const int h  = bh & (NH_ - 1);
  const int b  = bh >> 4;

  const int qbase  = qt * 64;
  const int qrow_w = qbase + wv * 16;   // wave's first q row (absolute)

  // ---- Q fragments, held in registers for the whole kernel ----
  const float* qptr = Qp + ((size_t)(b * S_ + qrow_w + r16)) * E_ + h * AH_;
  bf16x8 qh[2], ql[2];
#pragma unroll
  for (int c = 0; c < 2; ++c) {
    float4 v0 = *(const float4*)&qptr[c * 32 + hi4 * 8 + 0];
    float4 v1 = *(const float4*)&qptr[c * 32 + hi4 * 8 + 4];
    float f[8] = {v0.x, v0.y, v0.z, v0.w, v1.x, v1.y, v1.z, v1.w};
    bf16x8 hh, ll;
#pragma unroll
    for (int j = 0; j < 8; ++j) {
      unsigned short hq, lq;
      split_bf16(f[j], hq, lq);
      hh[j] = (short)hq;
      ll[j] = (short)lq;
    }
    qh[c] = hh;
    ql[c] = ll;
  }

  float m[4], l[4];
  f32x4 oacc[4];
#pragma unroll
  for (int r = 0; r < 4; ++r) { m[r] = -3.0e38f; l[r] = 0.f; }
#pragma unroll
  for (int dt = 0; dt < 4; ++dt) {
    f32x4 z = {0.f, 0.f, 0.f, 0.f};
    oacc[dt] = z;
  }

  // staging maps
  const int skey = tid >> 2;            // K stage: key 0..63
  const int sdq  = (tid & 3) << 4;      // K stage: d group of 16
  const int vkp  = tid & 31;            // V stage: key pair (2*vkp, 2*vkp+1)
  const int vdb  = (tid >> 5) << 3;     // V stage: d base (8 d's)

  const int ktiles = causal ? (qt + 1) : (S_ / 64);

  for (int kt = 0; kt < ktiles; ++kt) {
    const int kb = kt * 64;

    // ---- stage K tile [key][d] ----
    {
      const float* kr = Kp + ((size_t)(b * S_ + kb + skey)) * E_ + h * AH_ + sdq;
#pragma unroll
      for (int i = 0; i < 4; ++i) {
        float4 v = *(const float4*)&kr[4 * i];
        unsigned short h0, h1, h2, h3, l0, l1, l2, l3;
        split_bf16(v.x, h0, l0);
        split_bf16(v.y, h1, l1);
        split_bf16(v.z, h2, l2);
        split_bf16(v.w, h3, l3);
        us4 hv = {h0, h1, h2, h3};
        us4 lv = {l0, l1, l2, l3};
        *(us4*)&Khi[skey * KP_ + sdq + 4 * i] = hv;
        *(us4*)&Klo[skey * KP_ + sdq + 4 * i] = lv;
      }
    }
    // ---- stage V tile transposed [d][key] ----
    {
      const float* vr0 = Vp + ((size_t)(b * S_ + kb + 2 * vkp)) * E_ + h * AH_ + vdb;
      const float* vr1 = vr0 + E_;
      float4 a0 = *(const float4*)&vr0[0];
      float4 a1 = *(const float4*)&vr0[4];
      float4 b0 = *(const float4*)&vr1[0];
      float4 b1 = *(const float4*)&vr1[4];
      float xa[8] = {a0.x, a0.y, a0.z, a0.w, a1.x, a1.y, a1.z, a1.w};
      float xb[8] = {b0.x, b0.y, b0.z, b0.w, b1.x, b1.y, b1.z, b1.w};
#pragma unroll
      for (int d = 0; d < 8; ++d) {
        unsigned short ha, la, hb, lb;
        split_bf16(xa[d], ha, la);
        split_bf16(xb[d], hb, lb);
        *(unsigned*)&Vhi[(vdb + d) * KP_ + 2 * vkp] = (unsigned)ha | ((unsigned)hb << 16);
        *(unsigned*)&Vlo[(vdb + d) * KP_ + 2 * vkp] = (unsigned)la | ((unsigned)lb << 16);
      }
    }
    __syncthreads();

    // ---- S = Q K^T (16 q x 64 keys per wave) ----
    f32x4 sacc[4];
#pragma unroll
    for (int n = 0; n < 4; ++n) {
      f32x4 s = {0.f, 0.f, 0.f, 0.f};
#pragma unroll
      for (int c = 0; c < 2; ++c) {
        bf16x8 kh = *(const bf16x8*)&Khi[(n * 16 + r16) * KP_ + c * 32 + hi4 * 8];
        bf16x8 kl = *(const bf16x8*)&Klo[(n * 16 + r16) * KP_ + c * 32 + hi4 * 8];
        s = __builtin_amdgcn_mfma_f32_16x16x32_bf16(qh[c], kh, s, 0, 0, 0);
        s = __builtin_amdgcn_mfma_f32_16x16x32_bf16(ql[c], kh, s, 0, 0, 0);
        s = __builtin_amdgcn_mfma_f32_16x16x32_bf16(qh[c], kl, s, 0, 0, 0);
      }
      sacc[n] = s;
    }

    // ---- scale + causal mask ----
#pragma unroll
    for (int n = 0; n < 4; ++n)
#pragma unroll
      for (int r = 0; r < 4; ++r) {
        float sv = sacc[n][r] * 0.125f;
        if (causal && (kb + n * 16 + r16) > (qrow_w + hi4 * 4 + r)) sv = -1.0e9f;
        sacc[n][r] = sv;
      }

    // ---- online softmax (row state per lane for its 4 q rows) ----
    float pm[4];
#pragma unroll
    for (int r = 0; r < 4; ++r)
      pm[r] = fmaxf(fmaxf(sacc[0][r], sacc[1][r]), fmaxf(sacc[2][r], sacc[3][r]));
#pragma unroll
    for (int off = 1; off < 16; off <<= 1)
#pragma unroll
      for (int r = 0; r < 4; ++r) pm[r] = fmaxf(pm[r], __shfl_xor(pm[r], off, 16));

    float alpha[4];
#pragma unroll
    for (int r = 0; r < 4; ++r) {
      float mn = fmaxf(m[r], pm[r]);
      alpha[r] = expf(m[r] - mn);
      m[r] = mn;
    }

    float tsum[4] = {0.f, 0.f, 0.f, 0.f};
#pragma unroll
    for (int n = 0; n < 4; ++n)
#pragma unroll
      for (int r = 0; r < 4; ++r) {
        float p = expf(sacc[n][r] - m[r]);   // masked entries underflow to 0
        sacc[n][r] = p;
        tsum[r] += p;
      }
#pragma unroll
    for (int off = 1; off < 16; off <<= 1)
#pragma unroll
      for (int r = 0; r < 4; ++r) tsum[r] += __shfl_xor(tsum[r], off, 16);
#pragma unroll
    for (int r = 0; r < 4; ++r) l[r] = l[r] * alpha[r] + tsum[r];
#pragma unroll
    for (int dt = 0; dt < 4; ++dt)
#pragma unroll
      for (int r = 0; r < 4; ++r) oacc[dt][r] *= alpha[r];

    // ---- P (C-layout) -> per-wave LDS [q][key] as hi/lo bf16 ----
#pragma unroll
    for (int n = 0; n < 4; ++n)
#pragma unroll
      for (int r = 0; r < 4; ++r) {
        unsigned short ph, pl;
        split_bf16(sacc[n][r], ph, pl);
        const int q = hi4 * 4 + r;
        Phi[wv][q * KP_ + n * 16 + r16] = ph;
        Plo[wv][q * KP_ + n * 16 + r16] = pl;
      }
    asm volatile("s_waitcnt lgkmcnt(0)" ::: "memory");

    // ---- O += P V (A = P [q][k], B = V^T [d][k]) ----
    bf16x8 pah[2], pal[2];
#pragma unroll
    for (int c = 0; c < 2; ++c) {
      pah[c] = *(const bf16x8*)&Phi[wv][r16 * KP_ + c * 32 + hi4 * 8];
      pal[c] = *(const bf16x8*)&Plo[wv][r16 * KP_ + c * 32 + hi4 * 8];
    }
#pragma unroll
    for (int dt = 0; dt < 4; ++dt) {
      f32x4 o = oacc[dt];
#pragma unroll
      for (int c = 0; c < 2; ++c) {
        bf16x8 vbh = *(const bf16x8*)&Vhi[(dt * 16 + r16) * KP_ + c * 32 + hi4 * 8];
        bf16x8 vbl = *(const bf16x8*)&Vlo[(dt * 16 + r16) * KP_ + c * 32 + hi4 * 8];
        o = __builtin_amdgcn_mfma_f32_16x16x32_bf16(pah[c], vbh, o, 0, 0, 0);
        o = __builtin_amdgcn_mfma_f32_16x16x32_bf16(pal[c], vbh, o, 0, 0, 0);
        o = __builtin_amdgcn_mfma_f32_16x16x32_bf16(pah[c], vbl, o, 0, 0, 0);
      }
      oacc[dt] = o;
    }
    __syncthreads();
  }

  // ---- epilogue: O = oacc / l ----
#pragma unroll
  for (int r = 0; r < 4; ++r) {
    const float invl = 1.0f / l[r];
    const size_t base = ((size_t)(b * S_ + qrow_w + hi4 * 4 + r)) * E_ + h * AH_;
#pragma unroll
    for (int dt = 0; dt < 4; ++dt) {
      Op[base + dt * 16 + r16] = oacc[dt][r] * invl;
    }
  }
}

// ---------------------------------------------------------------------------
// out[row] = LayerNorm(X[row] + R[row]) * g + b   (unchanged)
// ---------------------------------------------------------------------------
__global__ __launch_bounds__(256) void add_ln_kernel(const float* __restrict__ X,
                                                     const float* __restrict__ R,
                                                     const float* __restrict__ g,
                                                     const float* __restrict__ bta,
                                                     float* __restrict__ out) {
  __shared__ float s1[4], s2[4];
  const int row = blockIdx.x;
  const int tid = threadIdx.x;
  const size_t base = (size_t)row * E_;
  const int e = tid * 4;

  float4 xv = *(const float4*)&X[base + e];
  float4 rv = *(const float4*)&R[base + e];
  float v0 = xv.x + rv.x, v1 = xv.y + rv.y, v2 = xv.z + rv.z, v3 = xv.w + rv.w;

  float sum = v0 + v1 + v2 + v3;
  float sq  = v0 * v0 + v1 * v1 + v2 * v2 + v3 * v3;
#pragma unroll
  for (int off = 32; off; off >>= 1) {
    sum += __shfl_xor(sum, off, 64);
    sq  += __shfl_xor(sq,  off, 64);
  }
  if ((tid & 63) == 0) { s1[tid >> 6] = sum; s2[tid >> 6] = sq; }
  __syncthreads();
  sum = s1[0] + s1[1] + s1[2] + s1[3];
  sq  = s2[0] + s2[1] + s2[2] + s2[3];

  const float mean = sum * (1.0f / E_);
  const float var  = sq * (1.0f / E_) - mean * mean;
  const float rs   = rsqrtf(var + 1e-5f);

  float4 gv = *(const float4*)&g[e];
  float4 bv = *(const float4*)&bta[e];
  float4 o;
  o.x = (v0 - mean) * rs * gv.x + bv.x;
  o.y = (v1 - mean) * rs * gv.y + bv.y;
  o.z = (v2 - mean) * rs * gv.z + bv.z;
  o.w = (v3 - mean) * rs * gv.w + bv.w;
  *(float4*)&out[base + e] = o;
}

// ---------------------------------------------------------------------------
extern "C" void kernel_launch(void* const* d_in, const int* in_sizes, int n_in,
                              void* d_out, int out_size, void* d_ws, size_t ws_size,
                              hipStream_t stream) {
  const float* x       = (const float*)d_in[0];
  const float* y       = (const float*)d_in[1];
  const float* enc_wq  = (const float*)d_in[2];
  const float* enc_wk  = (const float*)d_in[3];
  const float* enc_wv  = (const float*)d_in[4];
  const float* enc_wo  = (const float*)d_in[5];
  const float* enc_bo  = (const float*)d_in[6];
  const float* enc_ln1g = (const float*)d_in[7];
  const float* enc_ln1b = (const float*)d_in[8];
  const float* enc_ln2g = (const float*)d_in[9];
  const float* enc_ln2b = (const float*)d_in[10];
  const float* enc_f1w = (const float*)d_in[11];
  const float* enc_f1b = (const float*)d_in[12];
  const float* enc_f2w = (const float*)d_in[13];
  const float* enc_f2b = (const float*)d_in[14];
  const float* dec_wq1 = (const float*)d_in[15];
  const float* dec_wk1 = (const float*)d_in[16];
  const float* dec_wv1 = (const float*)d_in[17];
  const float* dec_wo1 = (const float*)d_in[18];
  const float* dec_bo1 = (const float*)d_in[19];
  const float* dec_wq2 = (const float*)d_in[20];
  const float* dec_wk2 = (const float*)d_in[21];
  const float* dec_wv2 = (const float*)d_in[22];
  const float* dec_wo2 = (const float*)d_in[23];
  const float* dec_bo2 = (const float*)d_in[24];
  const float* dec_ln1g = (const float*)d_in[25];
  const float* dec_ln1b = (const float*)d_in[26];
  const float* dec_ln2g = (const float*)d_in[27];
  const float* dec_ln2b = (const float*)d_in[28];
  const float* dec_ln3g = (const float*)d_in[29];
  const float* dec_ln3b = (const float*)d_in[30];
  const float* dec_f1w = (const float*)d_in[31];
  const float* dec_f1b = (const float*)d_in[32];
  const float* dec_f2w = (const float*)d_in[33];
  const float* dec_f2b = (const float*)d_in[34];
  const float* cls_w1  = (const float*)d_in[35];
  const float* cls_b1  = (const float*)d_in[36];
  const float* cls_w2  = (const float*)d_in[37];
  const float* cls_b2  = (const float*)d_in[38];
  const float* cls_w3  = (const float*)d_in[39];
  const float* cls_b3  = (const float*)d_in[40];

  float* ws = (float*)d_ws;
  const size_t TE = (size_t)T_ * E_;   // 2M floats
  float* EX = ws + 0 * TE;             // encoder activations / encs
  float* DX = ws + 1 * TE;             // decoder activations
  float* Qb = ws + 2 * TE;
  float* Kb = ws + 3 * TE;
  float* Vb = ws + 4 * TE;
  float* AT = ws + 5 * TE;             // attention output (pre-Wo)
  float* T1 = ws + 6 * TE;
  float* T2 = ws + 7 * TE;
  float* H1 = ws + 2 * TE;             // classifier hidden 1 (2*TE floats)
  float* H2 = ws + 4 * TE;             // classifier hidden 2 (2*TE floats)

  auto gemm = [&](const float* A, const float* W, const float* bias, float* C,
                  int M, int N, int K, int relu) {
    dim3 grid(M / 128, N / 128);       // x = M-blocks: consecutive blocks share B panel
    gemm_bf16x3<<<grid, 256, 0, stream>>>(A, W, bias, C, M, N, K, relu);
  };
  auto attn = [&](const float* Qp, const float* Kp, const float* Vp, float* Op,
                  int causal) {
    dim3 grid(S_ / 64, B_ * NH_);      // (q-tiles, b*h)
    attn_mfma<<<grid, 256, 0, stream>>>(Qp, Kp, Vp, Op, causal);
  };
  auto add_ln = [&](const float* Xp, const float* Rp, const float* g,
                    const float* bb, float* Op) {
    add_ln_kernel<<<T_, 256, 0, stream>>>(Xp, Rp, g, bb, Op);
  };

  const int total = T_ * E_;
  add_pe_kernel<<<(total + 255) / 256, 256, 0, stream>>>(x, EX, total);
  add_pe_kernel<<<(total + 255) / 256, 256, 0, stream>>>(y, DX, total);

  // ---------------- encoder ----------------
  for (int i = 0; i < NL_; ++i) {
    const size_t wOff = (size_t)i * EE_;
    const size_t vOff = (size_t)i * E_;
    gemm(EX, enc_wq + wOff, nullptr, Qb, T_, E_, E_, 0);
    gemm(EX, enc_wk + wOff, nullptr, Kb, T_, E_, E_, 0);
    gemm(EX, enc_wv + wOff, nullptr, Vb, T_, E_, E_, 0);
    attn(Qb, Kb, Vb, AT, 0);
    gemm(AT, enc_wo + wOff, enc_bo + vOff, T1, T_, E_, E_, 0);
    add_ln(T1, EX, enc_ln1g + vOff, enc_ln1b + vOff, T2);      // fx
    gemm(T2, enc_f1w + wOff, enc_f1b + vOff, T1, T_, E_, E_, 1);
    gemm(T1, enc_f2w + wOff, enc_f2b + vOff, Qb, T_, E_, E_, 0);
    add_ln(Qb, EX, enc_ln2g + vOff, enc_ln2b + vOff, EX);      // residual to block input
  }
  // EX now holds encs

  // ---------------- decoder ----------------
  for (int i = 0; i < NL_; ++i) {
    const size_t wOff = (size_t)i * EE_;
    const size_t vOff = (size_t)i * E_;
    // masked self-attention
    gemm(DX, dec_wq1 + wOff, nullptr, Qb, T_, E_, E_, 0);
    gemm(DX, dec_wk1 + wOff, nullptr, Kb, T_, E_, E_, 0);
    gemm(DX, dec_wv1 + wOff, nullptr, Vb, T_, E_, E_, 0);
    attn(Qb, Kb, Vb, AT, 1);
    gemm(AT, dec_wo1 + wOff, dec_bo1 + vOff, T1, T_, E_, E_, 0);
    add_ln(T1, DX, dec_ln1g + vOff, dec_ln1b + vOff, T2);      // f1
    // cross-attention (q from f1, k/v from encs)
    gemm(T2, dec_wq2 + wOff, nullptr, Qb, T_, E_, E_, 0);
    gemm(EX, dec_wk2 + wOff, nullptr, Kb, T_, E_, E_, 0);
    gemm(EX, dec_wv2 + wOff, nullptr, Vb, T_, E_, E_, 0);
    attn(Qb, Kb, Vb, AT, 0);
    gemm(AT, dec_wo2 + wOff, dec_bo2 + vOff, T1, T_, E_, E_, 0);
    add_ln(T1, DX, dec_ln2g + vOff, dec_ln2b + vOff, T2);      // f2
    // FFN
    gemm(T2, dec_f1w + wOff, dec_f1b + vOff, T1, T_, E_, E_, 1);
    gemm(T1, dec_f2w + wOff, dec_f2b + vOff, Qb, T_, E_, E_, 0);
    add_ln(Qb, DX, dec_ln3g + vOff, dec_ln3b + vOff, DX);      // residual to block input
  }

  // ---------------- classifier ----------------
  gemm(DX, cls_w1, cls_b1, H1, T_, HC_, E_, 1);
  gemm(H1, cls_w2, cls_b2, H2, T_, HC_, HC_, 1);
  gemm(H2, cls_w3, cls_b3, (float*)d_out, T_, V_, HC_, 0);
}